// Round 3
// baseline (217.859 us; speedup 1.0000x reference)
//
#include <hip/hip_runtime.h>
#include <hip/hip_bf16.h>

#define N 4096
#define IND 256
#define OUTD 128
#define NEGV -9000000000000000.0f

// ---------------- Kernel A: wh = lstm_out @ W  (4096x256 @ 256x128) ----------------
__global__ __launch_bounds__(256) void wh_kernel(const float* __restrict__ x,
                                                 const float* __restrict__ W,
                                                 float* __restrict__ wh) {
    __shared__ float xs[16][IND];
    const int t = threadIdx.x;
    const int i0 = blockIdx.x * 16;
    const float4* src = (const float4*)(x + (size_t)i0 * IND);
    float4* dst = (float4*)&xs[0][0];
    #pragma unroll
    for (int q = 0; q < 4; ++q) dst[t + q * 256] = src[t + q * 256];
    __syncthreads();
    const int c = t & 127;
    const int rh = t >> 7;
    float acc[8];
    #pragma unroll
    for (int r = 0; r < 8; ++r) acc[r] = 0.f;
    for (int k = 0; k < IND; ++k) {
        float w = W[k * OUTD + c];
        #pragma unroll
        for (int r = 0; r < 8; ++r) acc[r] = fmaf(xs[rh * 8 + r][k], w, acc[r]);
    }
    #pragma unroll
    for (int r = 0; r < 8; ++r)
        wh[(size_t)(i0 + rh * 8 + r) * OUTD + c] = acc[r];
}

// ---------------- Kernel A2: s_i = wh @ a_i, s_j = wh @ a_j ----------------
__global__ __launch_bounds__(128) void sij_kernel(const float* __restrict__ wh,
                                                  const float* __restrict__ a,
                                                  float* __restrict__ s_i,
                                                  float* __restrict__ s_j) {
    const int i = blockIdx.x;
    const int c = threadIdx.x;
    float v = wh[(size_t)i * OUTD + c];
    float p = v * a[c];              // a_i = a[0:128]
    float q = v * a[OUTD + 5 + c];   // a_j = a[133:261]
    #pragma unroll
    for (int off = 32; off >= 1; off >>= 1) {
        p += __shfl_down(p, off);
        q += __shfl_down(q, off);
    }
    __shared__ float tmp[4];
    if ((c & 63) == 0) { tmp[c >> 6] = p; tmp[2 + (c >> 6)] = q; }
    __syncthreads();
    if (c == 0) { s_i[i] = tmp[0] + tmp[1]; s_j[i] = tmp[2] + tmp[3]; }
}

// ---------------- Kernel B: per-(8-row, 512-j-chunk) partial attention ----------------
// Grid = 512 i-groups x 8 chunks = 4096 blocks of 512 threads (8 waves).
// Phase 1: wave r owns row i0+r; lane s handles j = j0+s+64k, k=0..7. Scores stay
//   in registers; single max/sum reduce over the wave (no online update needed —
//   one chunk per block). exp(P) -> LDS.
// Phase 2: c4 = 4*(t&31) (4 cols/thread, float4), js = t>>5 (16 slices x 32 j).
//   Per P b128 read -> 16 FMA; per wh float4 load -> 32 FMA.
// Merge: shfl_xor(32) folds odd js into even; 3-round LDS tree (red overlays P);
//   wave 0 writes the chunk partial + (m,l) to workspace.
#define BI 8
#define BJ 512
#define NCH (N / BJ)      // 8
#define PSTR 528          // P row stride (16-float aligned)
#define RSTR 132          // red row stride (4-float aligned)

__global__ __launch_bounds__(512, 7) void gat_part(const float* __restrict__ edges,
                                                   const float* __restrict__ wh,
                                                   const float* __restrict__ s_iv,
                                                   const float* __restrict__ s_jv,
                                                   const float* __restrict__ a,
                                                   float* __restrict__ part,
                                                   float* __restrict__ mout,
                                                   float* __restrict__ lout) {
    __shared__ float P[BI * PSTR];   // 16.9 KB; overlaid by red[4][BI][RSTR] after phase 2
    const int t = threadIdx.x;
    const int ib = blockIdx.x & 511;
    const int ch = blockIdx.x >> 9;
    const int i0 = ib * BI;
    const int j0 = ch * BJ;

    const int r = t >> 6;     // wave id == row index in block
    const int s = t & 63;
    const int i = i0 + r;

    // ---- phase 1: scores for row i over [j0, j0+512) ----
    {
        const float ae0 = a[OUTD + 0], ae1 = a[OUTD + 1], ae2 = a[OUTD + 2],
                    ae3 = a[OUTD + 3], ae4 = a[OUTD + 4];
        const float si = s_iv[i];
        float sc[8];
        float lmax = -1e30f;
        const float* eb = edges + ((size_t)i * N + (size_t)(j0 + s)) * 5;
        #pragma unroll
        for (int k = 0; k < 8; ++k) {
            const float* e = eb + k * (64 * 5);
            float d = e[4] * ae4;
            d = fmaf(e[0], ae0, d);
            d = fmaf(e[1], ae1, d);
            d = fmaf(e[2], ae2, d);
            d = fmaf(e[3], ae3, d);
            const int j = j0 + s + k * 64;
            float v = si + d + s_jv[j];
            v = fmaxf(v, 0.2f * v);       // leaky relu (before mask, matches ref)
            if (j == i) v = NEGV;
            sc[k] = v;
            lmax = fmaxf(lmax, v);
        }
        #pragma unroll
        for (int off = 32; off >= 1; off >>= 1)
            lmax = fmaxf(lmax, __shfl_xor(lmax, off));
        float lsum = 0.f;
        #pragma unroll
        for (int k = 0; k < 8; ++k) {
            const float p = __expf(sc[k] - lmax);
            P[r * PSTR + s + k * 64] = p;
            lsum += p;
        }
        #pragma unroll
        for (int off = 32; off >= 1; off >>= 1)
            lsum += __shfl_xor(lsum, off);
        if (s == 0) { mout[ch * N + i] = lmax; lout[ch * N + i] = lsum; }
    }
    __syncthreads();

    // ---- phase 2: PV partial, 4 cols/thread ----
    const int c4 = (t & 31) * 4;
    const int js = t >> 5;           // 0..15
    float4 acc[BI];
    #pragma unroll
    for (int rr = 0; rr < BI; ++rr) acc[rr] = make_float4(0.f, 0.f, 0.f, 0.f);
    {
        const float* whp = wh + (j0 + js * 32) * OUTD + c4;
        const int pb = js * 32;
        for (int jj = 0; jj < 32; jj += 4) {
            const float4 w0 = *(const float4*)(whp + (jj + 0) * OUTD);
            const float4 w1 = *(const float4*)(whp + (jj + 1) * OUTD);
            const float4 w2 = *(const float4*)(whp + (jj + 2) * OUTD);
            const float4 w3 = *(const float4*)(whp + (jj + 3) * OUTD);
            #pragma unroll
            for (int rr = 0; rr < BI; ++rr) {
                const float4 p = *(const float4*)&P[rr * PSTR + pb + jj];
                acc[rr].x = fmaf(p.x, w0.x, acc[rr].x);
                acc[rr].y = fmaf(p.x, w0.y, acc[rr].y);
                acc[rr].z = fmaf(p.x, w0.z, acc[rr].z);
                acc[rr].w = fmaf(p.x, w0.w, acc[rr].w);
                acc[rr].x = fmaf(p.y, w1.x, acc[rr].x);
                acc[rr].y = fmaf(p.y, w1.y, acc[rr].y);
                acc[rr].z = fmaf(p.y, w1.z, acc[rr].z);
                acc[rr].w = fmaf(p.y, w1.w, acc[rr].w);
                acc[rr].x = fmaf(p.z, w2.x, acc[rr].x);
                acc[rr].y = fmaf(p.z, w2.y, acc[rr].y);
                acc[rr].z = fmaf(p.z, w2.z, acc[rr].z);
                acc[rr].w = fmaf(p.z, w2.w, acc[rr].w);
                acc[rr].x = fmaf(p.w, w3.x, acc[rr].x);
                acc[rr].y = fmaf(p.w, w3.y, acc[rr].y);
                acc[rr].z = fmaf(p.w, w3.z, acc[rr].z);
                acc[rr].w = fmaf(p.w, w3.w, acc[rr].w);
            }
        }
    }
    // fold odd js (lanes 32-63) into even js (lanes 0-31)
    #pragma unroll
    for (int rr = 0; rr < BI; ++rr) {
        acc[rr].x += __shfl_xor(acc[rr].x, 32);
        acc[rr].y += __shfl_xor(acc[rr].y, 32);
        acc[rr].z += __shfl_xor(acc[rr].z, 32);
        acc[rr].w += __shfl_xor(acc[rr].w, 32);
    }
    __syncthreads();   // all P reads done; safe to overlay red

    float* red = P;
    const bool lo = (s < 32);
    // round 1: waves 4..7 -> slots 0..3; waves 0..3 add
    if (r >= 4 && lo) {
        #pragma unroll
        for (int rr = 0; rr < BI; ++rr)
            *(float4*)&red[((r - 4) * BI + rr) * RSTR + c4] = acc[rr];
    }
    __syncthreads();
    if (r < 4 && lo) {
        #pragma unroll
        for (int rr = 0; rr < BI; ++rr) {
            const float4 v = *(const float4*)&red[(r * BI + rr) * RSTR + c4];
            acc[rr].x += v.x; acc[rr].y += v.y; acc[rr].z += v.z; acc[rr].w += v.w;
        }
    }
    __syncthreads();
    // round 2: waves 2,3 -> slots 0,1; waves 0,1 add
    if (r >= 2 && r < 4 && lo) {
        #pragma unroll
        for (int rr = 0; rr < BI; ++rr)
            *(float4*)&red[((r - 2) * BI + rr) * RSTR + c4] = acc[rr];
    }
    __syncthreads();
    if (r < 2 && lo) {
        #pragma unroll
        for (int rr = 0; rr < BI; ++rr) {
            const float4 v = *(const float4*)&red[(r * BI + rr) * RSTR + c4];
            acc[rr].x += v.x; acc[rr].y += v.y; acc[rr].z += v.z; acc[rr].w += v.w;
        }
    }
    __syncthreads();
    // round 3: wave 1 -> slot 0; wave 0 adds and stores
    if (r == 1 && lo) {
        #pragma unroll
        for (int rr = 0; rr < BI; ++rr)
            *(float4*)&red[rr * RSTR + c4] = acc[rr];
    }
    __syncthreads();
    if (r == 0 && lo) {
        #pragma unroll
        for (int rr = 0; rr < BI; ++rr) {
            const float4 v = *(const float4*)&red[rr * RSTR + c4];
            acc[rr].x += v.x; acc[rr].y += v.y; acc[rr].z += v.z; acc[rr].w += v.w;
            *(float4*)&part[((size_t)ch * N + (i0 + rr)) * OUTD + c4] = acc[rr];
        }
    }
}

// ---------------- Kernel C: merge chunk partials ----------------
__global__ __launch_bounds__(256) void gat_merge(const float* __restrict__ part,
                                                 const float* __restrict__ mout,
                                                 const float* __restrict__ lout,
                                                 float* __restrict__ out) {
    const int idx = blockIdx.x * 256 + threadIdx.x;   // over N*OUTD
    const int i = idx >> 7;
    float M = -1e30f;
    #pragma unroll
    for (int k = 0; k < NCH; ++k) M = fmaxf(M, mout[k * N + i]);
    float L = 0.f, sacc = 0.f;
    #pragma unroll
    for (int k = 0; k < NCH; ++k) {
        const float e = __expf(mout[k * N + i] - M);
        L = fmaf(lout[k * N + i], e, L);
        sacc = fmaf(part[(size_t)k * (N * OUTD) + idx], e, sacc);
    }
    out[idx] = sacc / L;
}

extern "C" void kernel_launch(void* const* d_in, const int* in_sizes, int n_in,
                              void* d_out, int out_size, void* d_ws, size_t ws_size,
                              hipStream_t stream) {
    // inputs: 0=ids(int, unused), 1=lstm_out, 2=edges_list, 3=W, 4=a, 5=first(unused)
    const float* lstm_out = (const float*)d_in[1];
    const float* edges    = (const float*)d_in[2];
    const float* W        = (const float*)d_in[3];
    const float* a        = (const float*)d_in[4];
    float* out = (float*)d_out;

    float* wh   = (float*)d_ws;                  // 4096*128
    float* s_i  = wh + (size_t)N * OUTD;         // 4096
    float* s_j  = s_i + N;                       // 4096
    float* mout = s_j + N;                       // 8*4096
    float* lout = mout + (size_t)NCH * N;        // 8*4096
    float* part = lout + (size_t)NCH * N;        // 8*4096*128 (16.8 MB)

    wh_kernel<<<N / 16, 256, 0, stream>>>(lstm_out, W, wh);
    sij_kernel<<<N, 128, 0, stream>>>(wh, a, s_i, s_j);
    gat_part<<<512 * NCH, 512, 0, stream>>>(edges, wh, s_i, s_j, a, part, mout, lout);
    gat_merge<<<(N * OUTD) / 256, 256, 0, stream>>>(part, mout, lout, out);
}

// Round 4
// 153.058 us; speedup vs baseline: 1.4234x; 1.4234x over previous
//
#include <hip/hip_runtime.h>
#include <hip/hip_bf16.h>

#define N 4096
#define IND 256
#define OUTD 128
#define NEGV -9000000000000000.0f

// ---------------- Kernel A: wh = lstm_out @ W  (4096x256 @ 256x128) ----------------
__global__ __launch_bounds__(256) void wh_kernel(const float* __restrict__ x,
                                                 const float* __restrict__ W,
                                                 float* __restrict__ wh) {
    __shared__ float xs[16][IND];
    const int t = threadIdx.x;
    const int i0 = blockIdx.x * 16;
    const float4* src = (const float4*)(x + (size_t)i0 * IND);
    float4* dst = (float4*)&xs[0][0];
    #pragma unroll
    for (int q = 0; q < 4; ++q) dst[t + q * 256] = src[t + q * 256];
    __syncthreads();
    const int c = t & 127;
    const int rh = t >> 7;
    float acc[8];
    #pragma unroll
    for (int r = 0; r < 8; ++r) acc[r] = 0.f;
    for (int k = 0; k < IND; ++k) {
        float w = W[k * OUTD + c];
        #pragma unroll
        for (int r = 0; r < 8; ++r) acc[r] = fmaf(xs[rh * 8 + r][k], w, acc[r]);
    }
    #pragma unroll
    for (int r = 0; r < 8; ++r)
        wh[(size_t)(i0 + rh * 8 + r) * OUTD + c] = acc[r];
}

// ---------------- Kernel A2: s_i = wh @ a_i, s_j = wh @ a_j ----------------
__global__ __launch_bounds__(128) void sij_kernel(const float* __restrict__ wh,
                                                  const float* __restrict__ a,
                                                  float* __restrict__ s_i,
                                                  float* __restrict__ s_j) {
    const int i = blockIdx.x;
    const int c = threadIdx.x;
    float v = wh[(size_t)i * OUTD + c];
    float p = v * a[c];              // a_i = a[0:128]
    float q = v * a[OUTD + 5 + c];   // a_j = a[133:261]
    #pragma unroll
    for (int off = 32; off >= 1; off >>= 1) {
        p += __shfl_down(p, off);
        q += __shfl_down(q, off);
    }
    __shared__ float tmp[4];
    if ((c & 63) == 0) { tmp[c >> 6] = p; tmp[2 + (c >> 6)] = q; }
    __syncthreads();
    if (c == 0) { s_i[i] = tmp[0] + tmp[1]; s_j[i] = tmp[2] + tmp[3]; }
}

// ---------------- Kernel B: per-(8-row, 512-j-chunk) partial attention ----------------
// Grid = 512 i-groups x 8 chunks = 4096 blocks of 512 threads (8 waves).
// NOTE: launch_bounds(512, 3): round-3's (512,7) capped VGPR at ~73 -> compiler
// spilled the 32-reg float4 accumulator array to scratch (WRITE_SIZE showed 208 MB
// of spill traffic, VGPR_Count=36). Cap ~168 lets phase 2 live in registers.
#define BI 8
#define BJ 512
#define NCH (N / BJ)      // 8
#define PSTR 528          // P row stride (16-float aligned)
#define RSTR 132          // red row stride (4-float aligned)

__global__ __launch_bounds__(512, 3) void gat_part(const float* __restrict__ edges,
                                                   const float* __restrict__ wh,
                                                   const float* __restrict__ s_iv,
                                                   const float* __restrict__ s_jv,
                                                   const float* __restrict__ a,
                                                   float* __restrict__ part,
                                                   float* __restrict__ mout,
                                                   float* __restrict__ lout) {
    __shared__ float P[BI * PSTR];   // 16.9 KB; overlaid by red[4][BI][RSTR] after phase 2
    const int t = threadIdx.x;
    const int ib = blockIdx.x & 511;
    const int ch = blockIdx.x >> 9;
    const int i0 = ib * BI;
    const int j0 = ch * BJ;

    const int r = t >> 6;     // wave id == row index in block
    const int s = t & 63;
    const int i = i0 + r;

    // ---- phase 1: scores for row i over [j0, j0+512) ----
    {
        const float ae0 = a[OUTD + 0], ae1 = a[OUTD + 1], ae2 = a[OUTD + 2],
                    ae3 = a[OUTD + 3], ae4 = a[OUTD + 4];
        const float si = s_iv[i];
        float sc[8];
        float lmax = -1e30f;
        const float* eb = edges + ((size_t)i * N + (size_t)(j0 + s)) * 5;
        #pragma unroll
        for (int k = 0; k < 8; ++k) {
            const float* e = eb + k * (64 * 5);
            float d = e[4] * ae4;
            d = fmaf(e[0], ae0, d);
            d = fmaf(e[1], ae1, d);
            d = fmaf(e[2], ae2, d);
            d = fmaf(e[3], ae3, d);
            const int j = j0 + s + k * 64;
            float v = si + d + s_jv[j];
            v = fmaxf(v, 0.2f * v);       // leaky relu (before mask, matches ref)
            if (j == i) v = NEGV;
            sc[k] = v;
            lmax = fmaxf(lmax, v);
        }
        #pragma unroll
        for (int off = 32; off >= 1; off >>= 1)
            lmax = fmaxf(lmax, __shfl_xor(lmax, off));
        float lsum = 0.f;
        #pragma unroll
        for (int k = 0; k < 8; ++k) {
            const float p = __expf(sc[k] - lmax);
            P[r * PSTR + s + k * 64] = p;
            lsum += p;
        }
        #pragma unroll
        for (int off = 32; off >= 1; off >>= 1)
            lsum += __shfl_xor(lsum, off);
        if (s == 0) { mout[ch * N + i] = lmax; lout[ch * N + i] = lsum; }
    }
    __syncthreads();

    // ---- phase 2: PV partial, 4 cols/thread ----
    const int c4 = (t & 31) * 4;
    const int js = t >> 5;           // 0..15
    float4 acc[BI];
    #pragma unroll
    for (int rr = 0; rr < BI; ++rr) acc[rr] = make_float4(0.f, 0.f, 0.f, 0.f);
    {
        const float* whp = wh + (j0 + js * 32) * OUTD + c4;
        const int pb = js * 32;
        for (int jj = 0; jj < 32; jj += 4) {
            const float4 w0 = *(const float4*)(whp + (jj + 0) * OUTD);
            const float4 w1 = *(const float4*)(whp + (jj + 1) * OUTD);
            const float4 w2 = *(const float4*)(whp + (jj + 2) * OUTD);
            const float4 w3 = *(const float4*)(whp + (jj + 3) * OUTD);
            #pragma unroll
            for (int rr = 0; rr < BI; ++rr) {
                const float4 p = *(const float4*)&P[rr * PSTR + pb + jj];
                acc[rr].x = fmaf(p.x, w0.x, acc[rr].x);
                acc[rr].y = fmaf(p.x, w0.y, acc[rr].y);
                acc[rr].z = fmaf(p.x, w0.z, acc[rr].z);
                acc[rr].w = fmaf(p.x, w0.w, acc[rr].w);
                acc[rr].x = fmaf(p.y, w1.x, acc[rr].x);
                acc[rr].y = fmaf(p.y, w1.y, acc[rr].y);
                acc[rr].z = fmaf(p.y, w1.z, acc[rr].z);
                acc[rr].w = fmaf(p.y, w1.w, acc[rr].w);
                acc[rr].x = fmaf(p.z, w2.x, acc[rr].x);
                acc[rr].y = fmaf(p.z, w2.y, acc[rr].y);
                acc[rr].z = fmaf(p.z, w2.z, acc[rr].z);
                acc[rr].w = fmaf(p.z, w2.w, acc[rr].w);
                acc[rr].x = fmaf(p.w, w3.x, acc[rr].x);
                acc[rr].y = fmaf(p.w, w3.y, acc[rr].y);
                acc[rr].z = fmaf(p.w, w3.z, acc[rr].z);
                acc[rr].w = fmaf(p.w, w3.w, acc[rr].w);
            }
        }
    }
    // fold odd js (lanes 32-63) into even js (lanes 0-31)
    #pragma unroll
    for (int rr = 0; rr < BI; ++rr) {
        acc[rr].x += __shfl_xor(acc[rr].x, 32);
        acc[rr].y += __shfl_xor(acc[rr].y, 32);
        acc[rr].z += __shfl_xor(acc[rr].z, 32);
        acc[rr].w += __shfl_xor(acc[rr].w, 32);
    }
    __syncthreads();   // all P reads done; safe to overlay red

    float* red = P;
    const bool lo = (s < 32);
    // round 1: waves 4..7 -> slots 0..3; waves 0..3 add
    if (r >= 4 && lo) {
        #pragma unroll
        for (int rr = 0; rr < BI; ++rr)
            *(float4*)&red[((r - 4) * BI + rr) * RSTR + c4] = acc[rr];
    }
    __syncthreads();
    if (r < 4 && lo) {
        #pragma unroll
        for (int rr = 0; rr < BI; ++rr) {
            const float4 v = *(const float4*)&red[(r * BI + rr) * RSTR + c4];
            acc[rr].x += v.x; acc[rr].y += v.y; acc[rr].z += v.z; acc[rr].w += v.w;
        }
    }
    __syncthreads();
    // round 2: waves 2,3 -> slots 0,1; waves 0,1 add
    if (r >= 2 && r < 4 && lo) {
        #pragma unroll
        for (int rr = 0; rr < BI; ++rr)
            *(float4*)&red[((r - 2) * BI + rr) * RSTR + c4] = acc[rr];
    }
    __syncthreads();
    if (r < 2 && lo) {
        #pragma unroll
        for (int rr = 0; rr < BI; ++rr) {
            const float4 v = *(const float4*)&red[(r * BI + rr) * RSTR + c4];
            acc[rr].x += v.x; acc[rr].y += v.y; acc[rr].z += v.z; acc[rr].w += v.w;
        }
    }
    __syncthreads();
    // round 3: wave 1 -> slot 0; wave 0 adds and stores
    if (r == 1 && lo) {
        #pragma unroll
        for (int rr = 0; rr < BI; ++rr)
            *(float4*)&red[rr * RSTR + c4] = acc[rr];
    }
    __syncthreads();
    if (r == 0 && lo) {
        #pragma unroll
        for (int rr = 0; rr < BI; ++rr) {
            const float4 v = *(const float4*)&red[rr * RSTR + c4];
            acc[rr].x += v.x; acc[rr].y += v.y; acc[rr].z += v.z; acc[rr].w += v.w;
            *(float4*)&part[((size_t)ch * N + (i0 + rr)) * OUTD + c4] = acc[rr];
        }
    }
}

// ---------------- Kernel C: merge chunk partials ----------------
__global__ __launch_bounds__(256) void gat_merge(const float* __restrict__ part,
                                                 const float* __restrict__ mout,
                                                 const float* __restrict__ lout,
                                                 float* __restrict__ out) {
    const int idx = blockIdx.x * 256 + threadIdx.x;   // over N*OUTD
    const int i = idx >> 7;
    float M = -1e30f;
    #pragma unroll
    for (int k = 0; k < NCH; ++k) M = fmaxf(M, mout[k * N + i]);
    float L = 0.f, sacc = 0.f;
    #pragma unroll
    for (int k = 0; k < NCH; ++k) {
        const float e = __expf(mout[k * N + i] - M);
        L = fmaf(lout[k * N + i], e, L);
        sacc = fmaf(part[(size_t)k * (N * OUTD) + idx], e, sacc);
    }
    out[idx] = sacc / L;
}

extern "C" void kernel_launch(void* const* d_in, const int* in_sizes, int n_in,
                              void* d_out, int out_size, void* d_ws, size_t ws_size,
                              hipStream_t stream) {
    // inputs: 0=ids(int, unused), 1=lstm_out, 2=edges_list, 3=W, 4=a, 5=first(unused)
    const float* lstm_out = (const float*)d_in[1];
    const float* edges    = (const float*)d_in[2];
    const float* W        = (const float*)d_in[3];
    const float* a        = (const float*)d_in[4];
    float* out = (float*)d_out;

    float* wh   = (float*)d_ws;                  // 4096*128
    float* s_i  = wh + (size_t)N * OUTD;         // 4096
    float* s_j  = s_i + N;                       // 4096
    float* mout = s_j + N;                       // 8*4096
    float* lout = mout + (size_t)NCH * N;        // 8*4096
    float* part = lout + (size_t)NCH * N;        // 8*4096*128 (16.8 MB)

    wh_kernel<<<N / 16, 256, 0, stream>>>(lstm_out, W, wh);
    sij_kernel<<<N, 128, 0, stream>>>(wh, a, s_i, s_j);
    gat_part<<<512 * NCH, 512, 0, stream>>>(edges, wh, s_i, s_j, a, part, mout, lout);
    gat_merge<<<(N * OUTD) / 256, 256, 0, stream>>>(part, mout, lout, out);
}